// Round 4
// baseline (1225.771 us; speedup 1.0000x reference)
//
#include <hip/hip_runtime.h>
#include <hip/hip_bf16.h>

// Problem constants
#define BB 8
#define CC 128
#define NN 16384            // 128*128 tokens per batch
#define MM (BB * NN)        // 131072
#define NCH 128             // scan chunks per batch-row
#define CLN 128             // chunk length == GEMM tile M

typedef __attribute__((ext_vector_type(8))) short short8;   // 8 x bf16 (4 VGPRs)
typedef __attribute__((ext_vector_type(4))) float floatx4;  // MFMA accumulator
typedef unsigned short u16;
typedef unsigned int u32;

__device__ __forceinline__ float bf2f(u16 h) {
  u32 u = ((u32)h) << 16;
  return __builtin_bit_cast(float, u);
}
__device__ __forceinline__ u16 f2bf(float f) {
  u32 u = __builtin_bit_cast(u32, f);
  u32 r = u + 0x7FFFu + ((u >> 16) & 1u);   // round-to-nearest-even
  return (u16)(r >> 16);
}

// ---------------------------------------------------------------------------
// FiLM params: gamma[b,c] = gs[b,:]·cond_gw[c,:] + cond_gb[c]; beta likewise.
__global__ void film_kernel(const float* __restrict__ gs, const float* __restrict__ gw,
                            const float* __restrict__ gb, const float* __restrict__ bw,
                            const float* __restrict__ bb, float* __restrict__ gamma,
                            float* __restrict__ beta) {
  int idx = blockIdx.x * 256 + threadIdx.x;   // 0..1023
  int b = idx >> 7, c = idx & 127;
  float sg = 0.f, sb = 0.f;
  for (int j = 0; j < 128; ++j) {
    float g = gs[b * 128 + j];
    sg += g * gw[c * 128 + j];
    sb += g * bw[c * 128 + j];
  }
  gamma[idx] = sg + gb[c];
  beta[idx] = sb + bb[c];
}

// ---------------------------------------------------------------------------
// Convert all 6 weight tensors (each (2,128,128) f32) to bf16, packed
// [which][block][o][c] at dst + which*32768.
__global__ void convert_kernel(const float* __restrict__ Wk, const float* __restrict__ Wv,
                               const float* __restrict__ Wr, const float* __restrict__ Wo,
                               const float* __restrict__ gp, const float* __restrict__ bp,
                               u16* __restrict__ dst) {
  int idx = blockIdx.x * 256 + threadIdx.x;   // 0..196607
  int which = idx >> 15;
  int off = idx & 32767;
  const float* s;
  switch (which) {
    case 0: s = Wk; break; case 1: s = Wv; break; case 2: s = Wr; break;
    case 3: s = Wo; break; case 4: s = gp; break; default: s = bp; break;
  }
  dst[idx] = f2bf(s[off]);
}

// ---------------------------------------------------------------------------
// Prep: (UPS=1) bilinear 2x upsample + write x_up to out(BCHW) + FiLM + LN -> xn bf16
//       (UPS=0) read out(BCHW) + LN -> xn bf16
template <int UPS>
__global__ __launch_bounds__(256) void prep_kernel(
    const float* __restrict__ src, const float* __restrict__ gamma,
    const float* __restrict__ beta, const float* __restrict__ lng,
    const float* __restrict__ lnb, float* __restrict__ outp, u16* __restrict__ xn) {
  __shared__ float tile[64][129];
  __shared__ float smu[64], srs[64];
  int bidx = blockIdx.x;              // 0..2047
  int half = bidx & 1;
  int ho = (bidx >> 1) & 127;
  int b = bidx >> 8;
  int wo0 = half * 64;
  int tid = threadIdx.x;
  int tk = tid & 63;
  int wo = wo0 + tk;
  int c0 = tid >> 6;                  // 0..3
  int j0 = 0, j1 = 0, i0 = 0, i1 = 0;
  float wy0 = 0.f, wy1 = 0.f, wx0 = 0.f, wx1 = 0.f;
  if (UPS) {
    int jj = ho >> 1;
    if ((ho & 1) == 0) { j0 = jj > 0 ? jj - 1 : 0; j1 = jj; wy0 = 0.25f; wy1 = 0.75f; }
    else               { j0 = jj; j1 = jj < 63 ? jj + 1 : 63; wy0 = 0.75f; wy1 = 0.25f; }
    int ii = wo >> 1;
    if ((wo & 1) == 0) { i0 = ii > 0 ? ii - 1 : 0; i1 = ii; wx0 = 0.25f; wx1 = 0.75f; }
    else               { i0 = ii; i1 = ii < 63 ? ii + 1 : 63; wx0 = 0.75f; wx1 = 0.25f; }
  }
  for (int it = 0; it < 32; ++it) {
    int c = it * 4 + c0;
    float v;
    if (UPS) {
      const float* xp = src + ((size_t)(b * 128 + c)) * 4096;
      v = wy0 * (wx0 * xp[j0 * 64 + i0] + wx1 * xp[j0 * 64 + i1]) +
          wy1 * (wx0 * xp[j1 * 64 + i0] + wx1 * xp[j1 * 64 + i1]);
      outp[((size_t)(b * 128 + c)) * 16384 + ho * 128 + wo] = v;
      v = v * (1.f + gamma[b * 128 + c]) + beta[b * 128 + c];
    } else {
      v = src[((size_t)(b * 128 + c)) * 16384 + ho * 128 + wo];
    }
    tile[tk][c] = v;
  }
  __syncthreads();
  {
    int token = tid >> 2, q = tid & 3;
    float s = 0.f, s2 = 0.f;
    for (int j = 0; j < 32; ++j) { float v = tile[token][q * 32 + j]; s += v; s2 += v * v; }
    s += __shfl_xor(s, 1); s2 += __shfl_xor(s2, 1);
    s += __shfl_xor(s, 2); s2 += __shfl_xor(s2, 2);
    if (q == 0) {
      float mu = s * 0.0078125f;
      float var = s2 * 0.0078125f - mu * mu;
      smu[token] = mu;
      srs[token] = rsqrtf(var + 1e-5f);
    }
  }
  __syncthreads();
  size_t base = ((size_t)b * 16384 + ho * 128 + wo0) * 128;
  for (int it = 0; it < 32; ++it) {
    int idx = it * 256 + tid;
    int token = idx >> 7, c = idx & 127;
    float v = (tile[token][c] - smu[token]) * srs[token] * lng[c] + lnb[c];
    xn[base + idx] = f2bf(v);
  }
}

// ---------------------------------------------------------------------------
// gemm_S: k-GEMM only, fused decay-weighted chunk sum -> Sbuf. No other output.
__global__ __launch_bounds__(256) void gemm_S_kernel(
    const u16* __restrict__ A, const u16* __restrict__ W0,
    const float* __restrict__ td, float* __restrict__ Sbuf) {
  __shared__ u16 Alds[128 * 128];
  __shared__ u16 Wlds[128 * 128];
  __shared__ float Sred[512];         // [wave][c]
  int tid = threadIdx.x;
  int wave = tid >> 6, lane = tid & 63;
  int l15 = lane & 15, l4 = lane >> 4;
  size_t row0 = (size_t)blockIdx.x * 128;
#pragma unroll
  for (int it = 0; it < 8; ++it) {
    int idx = it * 256 + tid;
    int rr = idx >> 4, s = idx & 15;
    uint4 d = *(const uint4*)(A + (row0 + rr) * 128 + s * 8);
    *(uint4*)(&Alds[rr * 128 + ((s ^ (rr & 15)) << 3)]) = d;
  }
#pragma unroll
  for (int it = 0; it < 8; ++it) {
    int idx = it * 256 + tid;
    int rr = idx >> 4, s = idx & 15;
    uint4 d = *(const uint4*)(W0 + rr * 128 + s * 8);
    *(uint4*)(&Wlds[rr * 128 + ((s ^ (rr & 15)) << 3)]) = d;
  }
  __syncthreads();
  floatx4 acc[2][8];
#pragma unroll
  for (int mi = 0; mi < 2; ++mi)
#pragma unroll
    for (int ni = 0; ni < 8; ++ni) acc[mi][ni] = (floatx4){0.f, 0.f, 0.f, 0.f};
#pragma unroll
  for (int kk = 0; kk < 4; ++kk) {
    int seg = kk * 4 + l4;
    short8 a0 = *(const short8*)(&Alds[(wave * 32 + l15) * 128 + ((seg ^ l15) << 3)]);
    short8 a1 = *(const short8*)(&Alds[(wave * 32 + 16 + l15) * 128 + ((seg ^ l15) << 3)]);
#pragma unroll
    for (int ni = 0; ni < 8; ++ni) {
      short8 bfr = *(const short8*)(&Wlds[(ni * 16 + l15) * 128 + ((seg ^ l15) << 3)]);
      acc[0][ni] = __builtin_amdgcn_mfma_f32_16x16x32_bf16(a0, bfr, acc[0][ni], 0, 0, 0);
      acc[1][ni] = __builtin_amdgcn_mfma_f32_16x16x32_bf16(a1, bfr, acc[1][ni], 0, 0, 0);
    }
  }
  // S_c = sum_tau d_c^{127-tau} k[tau][c]; tau = wave*32 + mi*16 + l4*4 + j
  int T0 = wave * 32 + l4 * 4;
#pragma unroll
  for (int ni = 0; ni < 8; ++ni) {
    int c = ni * 16 + l15;
    float a = fmaxf(td[c], 0.f);
    float E = __expf(-a * (float)(127 - T0));   // d^{127-T0}
    float r1 = __expf(a);                        // d^{-1}
    float r16 = __expf(a * 16.f);
    float w = E, sum;
    sum  = w * acc[0][ni][0]; w *= r1;
    sum += w * acc[0][ni][1]; w *= r1;
    sum += w * acc[0][ni][2]; w *= r1;
    sum += w * acc[0][ni][3];
    w = E * r16;
    sum += w * acc[1][ni][0]; w *= r1;
    sum += w * acc[1][ni][1]; w *= r1;
    sum += w * acc[1][ni][2]; w *= r1;
    sum += w * acc[1][ni][3];
    sum += __shfl_xor(sum, 16);
    sum += __shfl_xor(sum, 32);
    if (l4 == 0) Sred[wave * 128 + c] = sum;
  }
  __syncthreads();
  if (tid < 128) {
    float s = Sred[tid] + Sred[128 + tid] + Sred[256 + tid] + Sred[384 + tid];
    Sbuf[(blockIdx.x & 127) * 1024 + (blockIdx.x >> 7) * 128 + tid] = s;
  }
}

// ---------------------------------------------------------------------------
// Scan phase 2: per (b,c) scan over 128 chunks; one wave, 2 chunks per lane.
__global__ __launch_bounds__(256) void scan2_kernel(const float* __restrict__ S,
                                                    const float* __restrict__ td,
                                                    float* __restrict__ init) {
  int wave = threadIdx.x >> 6, lane = threadIdx.x & 63;
  int bc = blockIdx.x * 4 + wave;   // 0..1023
  int c = bc & 127;
  float a1 = __expf(-fmaxf(td[c], 0.f) * 128.f);   // decay^CLN
  float s0 = S[(2 * lane) * 1024 + bc];
  float s1 = S[(2 * lane + 1) * 1024 + bc];
  float s = s1 + a1 * s0;   // pair-combined segment sum
  float a = a1 * a1;
  for (int off = 1; off < 64; off <<= 1) {
    float ss = __shfl_up(s, off);
    float aa = __shfl_up(a, off);
    if (lane >= off) { s = s + a * ss; a = a * aa; }
  }
  float e = __shfl_up(s, 1);          // exclusive over pairs
  if (lane == 0) e = 0.f;
  init[(2 * lane) * 1024 + bc] = e;
  init[(2 * lane + 1) * 1024 + bc] = a1 * e + s0;
}

// ---------------------------------------------------------------------------
// Mega-tail: per (b, chunk of 128 tokens), two 64-token halves.
// Recomputes k,v,r from xn (v,r stay in MFMA accumulators), scans k via LDS,
// y = sigmoid(r)*(s+v) in registers, then Wo / gp / bp GEMMs and blend RMW.
__global__ __launch_bounds__(512, 4) void tail_kernel(
    const u16* __restrict__ xn, const float* __restrict__ init,
    const float* __restrict__ td,
    const u16* __restrict__ Wk, const u16* __restrict__ Wv, const u16* __restrict__ Wr,
    const u16* __restrict__ Wo, const u16* __restrict__ Wg, const u16* __restrict__ Wb,
    const float* __restrict__ gpb, const float* __restrict__ bpb,
    float* __restrict__ outp) {
  __shared__ u16 XN[8192];            // 16 KB: xn tile [tok][c] swz -> later T2 [tok][o]
  __shared__ u16 KLY[8192];           // 16 KB: k [c][tok^swz] -> later Y [tok][c] swz
  __shared__ u16 SLB[8192];           // 16 KB: s [c][tok^swz] -> later MB u32[64][64]
  __shared__ float SC[512];           // sub-chunk local sums [sub][c]
  __shared__ float CAR[128];          // cross-half state carry

  u16* T2 = XN;
  u32* MB = (u32*)SLB;

  int tid = threadIdx.x;
  int wave = tid >> 6, lane = tid & 63;
  int l15 = lane & 15, l4 = lane >> 4;
  int b = blockIdx.x >> 7;
  int chunk = blockIdx.x & 127;
  int tg = wave >> 1;                 // token group 0..3 (16 tokens)
  int ch = wave & 1;                  // channel half for kvr GEMMs
  int sc = tid & 127;                 // scan channel
  int sub = tid >> 7;                 // scan sub-chunk 0..3 (16 tokens)
  float sa_ = fmaxf(td[sc], 0.f);
  float sd_ = __expf(-sa_);
  float sd16_ = __expf(-sa_ * 16.f);
  int fc = sc & 60;

  for (int hf = 0; hf < 2; ++hf) {
    size_t gb = (size_t)b * 16384 + (size_t)chunk * 128 + hf * 64;

    // ---- 1: stage xn half-tile ----
#pragma unroll
    for (int it = 0; it < 2; ++it) {
      int idx = it * 512 + tid;
      int rr = idx >> 4, s = idx & 15;
      uint4 d = *(const uint4*)(xn + (gb + rr) * 128 + s * 8);
      *(uint4*)(&XN[rr * 128 + ((s ^ (rr & 15)) << 3)]) = d;
    }
    __syncthreads();

    // ---- 2: k-GEMM, k -> KLY [c][tok ^ (c&60)] ----
    short8 afr[4];
#pragma unroll
    for (int kk = 0; kk < 4; ++kk)
      afr[kk] = *(const short8*)(&XN[(tg * 16 + l15) * 128 + (((kk * 4 + l4) ^ l15) << 3)]);
    {
      floatx4 ak[4];
#pragma unroll
      for (int ni = 0; ni < 4; ++ni) ak[ni] = (floatx4){0.f, 0.f, 0.f, 0.f};
#pragma unroll
      for (int kk = 0; kk < 4; ++kk) {
#pragma unroll
        for (int ni = 0; ni < 4; ++ni) {
          short8 bk = *(const short8*)(Wk + (ch * 64 + ni * 16 + l15) * 128 + kk * 32 + l4 * 8);
          ak[ni] = __builtin_amdgcn_mfma_f32_16x16x32_bf16(afr[kk], bk, ak[ni], 0, 0, 0);
        }
      }
#pragma unroll
      for (int ni = 0; ni < 4; ++ni) {
        int c = ch * 64 + ni * 16 + l15;
        int f = c & 60;
        int tb = tg * 16 + l4 * 4;
        u32 p0 = (u32)f2bf(ak[ni][0]) | ((u32)f2bf(ak[ni][1]) << 16);
        u32 p1 = (u32)f2bf(ak[ni][2]) | ((u32)f2bf(ak[ni][3]) << 16);
        *(u32*)(&KLY[c * 64 + (tb ^ f)]) = p0;
        *(u32*)(&KLY[c * 64 + (tb ^ f) + 2]) = p1;
      }
    }
    __syncthreads();

    // ---- 3: scan local sums per (c, sub) ----
    float ls = 0.f;
#pragma unroll
    for (int i = 0; i < 16; ++i)
      ls = ls * sd_ + bf2f(KLY[sc * 64 + ((sub * 16 + i) ^ fc)]);
    SC[sub * 128 + sc] = ls;
    float st0 = (hf == 0) ? init[chunk * 1024 + b * 128 + sc] : CAR[sc];
    __syncthreads();

    // ---- 4: v,r GEMMs (accs) + scan replay -> SLB, CAR ----
    floatx4 av[4], ar[4];
#pragma unroll
    for (int ni = 0; ni < 4; ++ni) {
      av[ni] = (floatx4){0.f, 0.f, 0.f, 0.f};
      ar[ni] = (floatx4){0.f, 0.f, 0.f, 0.f};
    }
#pragma unroll
    for (int kk = 0; kk < 4; ++kk) {
#pragma unroll
      for (int ni = 0; ni < 4; ++ni) {
        const u16* wrow = (const u16*)0;
        short8 bv = *(const short8*)(Wv + (ch * 64 + ni * 16 + l15) * 128 + kk * 32 + l4 * 8);
        short8 br = *(const short8*)(Wr + (ch * 64 + ni * 16 + l15) * 128 + kk * 32 + l4 * 8);
        (void)wrow;
        av[ni] = __builtin_amdgcn_mfma_f32_16x16x32_bf16(afr[kk], bv, av[ni], 0, 0, 0);
        ar[ni] = __builtin_amdgcn_mfma_f32_16x16x32_bf16(afr[kk], br, ar[ni], 0, 0, 0);
      }
    }
    {
      float st = st0;
#pragma unroll
      for (int j = 0; j < 3; ++j)
        if (j < sub) st = st * sd16_ + SC[j * 128 + sc];
#pragma unroll
      for (int i = 0; i < 16; i += 2) {
        st = st * sd_ + bf2f(KLY[sc * 64 + ((sub * 16 + i) ^ fc)]);
        u16 s0 = f2bf(st);
        st = st * sd_ + bf2f(KLY[sc * 64 + ((sub * 16 + i + 1) ^ fc)]);
        u16 s1 = f2bf(st);
        *(u32*)(&SLB[sc * 64 + ((sub * 16 + i) ^ fc)]) = (u32)s0 | ((u32)s1 << 16);
      }
      if (sub == 3) CAR[sc] = st;
    }
    __syncthreads();

    // ---- 5: y = sigmoid(r)*(s+v) -> Y (= KLY region, [tok][c] swz) ----
#pragma unroll
    for (int ni = 0; ni < 4; ++ni) {
      int c = ch * 64 + ni * 16 + l15;
      int f = c & 60;
      int tb = tg * 16 + l4 * 4;
      uint2 sv = *(const uint2*)(&SLB[c * 64 + (tb ^ f)]);
      float sarr[4] = {bf2f((u16)(sv.x & 0xffff)), bf2f((u16)(sv.x >> 16)),
                       bf2f((u16)(sv.y & 0xffff)), bf2f((u16)(sv.y >> 16))};
#pragma unroll
      for (int j = 0; j < 4; ++j) {
        float rv = 1.f / (1.f + __expf(-ar[ni][j]));
        float y = rv * (sarr[j] + av[ni][j]);
        int tok = tb + j;
        KLY[tok * 128 + ((((c >> 3) ^ (tok & 15)) << 3) | (c & 7))] = f2bf(y);
      }
    }
    __syncthreads();

    // ---- 6: GEMM1 t = Wo . y^T -> T2 (= XN region, [tok][o] swz) ----
    int ob1 = wave * 16;
    floatx4 a1[4];
#pragma unroll
    for (int ni = 0; ni < 4; ++ni) a1[ni] = (floatx4){0.f, 0.f, 0.f, 0.f};
#pragma unroll
    for (int kk = 0; kk < 4; ++kk) {
      short8 wof = *(const short8*)(Wo + (ob1 + l15) * 128 + kk * 32 + l4 * 8);
#pragma unroll
      for (int ni = 0; ni < 4; ++ni) {
        short8 yf = *(const short8*)(&KLY[(ni * 16 + l15) * 128 + (((kk * 4 + l4) ^ l15) << 3)]);
        a1[ni] = __builtin_amdgcn_mfma_f32_16x16x32_bf16(wof, yf, a1[ni], 0, 0, 0);
      }
    }
#pragma unroll
    for (int ni = 0; ni < 4; ++ni) {
      int tok = ni * 16 + l15;
#pragma unroll
      for (int j = 0; j < 4; j += 2) {
        int o = ob1 + l4 * 4 + j;
        u32 pack = (u32)f2bf(a1[ni][j]) | ((u32)f2bf(a1[ni][j + 1]) << 16);
        int pos = tok * 128 + ((((o >> 3) ^ (tok & 15)) << 3) | (o & 7));
        *(u32*)(&T2[pos]) = pack;
      }
    }
    __syncthreads();

    // ---- 7: GEMM2 g/bt = Wg/Wb . t^T ----
    floatx4 ag[4], ab[4];
#pragma unroll
    for (int ni = 0; ni < 4; ++ni) {
      ag[ni] = (floatx4){0.f, 0.f, 0.f, 0.f};
      ab[ni] = (floatx4){0.f, 0.f, 0.f, 0.f};
    }
#pragma unroll
    for (int kk = 0; kk < 4; ++kk) {
      short8 wgf = *(const short8*)(Wg + (ob1 + l15) * 128 + kk * 32 + l4 * 8);
      short8 wbf = *(const short8*)(Wb + (ob1 + l15) * 128 + kk * 32 + l4 * 8);
#pragma unroll
      for (int ni = 0; ni < 4; ++ni) {
        short8 tf = *(const short8*)(&T2[(ni * 16 + l15) * 128 + (((kk * 4 + l4) ^ l15) << 3)]);
        ag[ni] = __builtin_amdgcn_mfma_f32_16x16x32_bf16(wgf, tf, ag[ni], 0, 0, 0);
        ab[ni] = __builtin_amdgcn_mfma_f32_16x16x32_bf16(wbf, tf, ab[ni], 0, 0, 0);
      }
    }
    __syncthreads();

    // ---- 8: epilogue, two o-halves through MB (= SLB region) ----
#pragma unroll
    for (int h = 0; h < 2; ++h) {
      if ((wave >> 2) == h) {
        int orel0 = (wave & 3) * 16;
#pragma unroll
        for (int ni = 0; ni < 4; ++ni) {
          int tok = ni * 16 + l15;
#pragma unroll
          for (int j = 0; j < 4; ++j) {
            int orel = orel0 + l4 * 4 + j;
            int o = h * 64 + orel;
            float g = ag[ni][j] + gpb[o];
            float t1 = __expf(2.f * g);
            float m = 2.f - 2.f / (t1 + 1.f);          // 1 + tanh(g), inf-safe
            float bt = ab[ni][j] + bpb[o];
            MB[orel * 64 + ((((tok >> 3) ^ (orel & 7)) << 3) | (tok & 7))] =
                (u32)f2bf(m) | ((u32)f2bf(bt) << 16);
          }
        }
      }
      __syncthreads();
      {
        int orel = tid >> 3, seg = tid & 7;
        int sp = ((seg ^ (orel & 7)) << 3);
        uint4 mb0 = *(const uint4*)(&MB[orel * 64 + sp]);
        uint4 mb1 = *(const uint4*)(&MB[orel * 64 + sp + 4]);
        float* op = outp + ((size_t)(b * 128 + h * 64 + orel)) * 16384 +
                    chunk * 128 + hf * 64 + seg * 8;
        float4 o0 = *(float4*)op;
        float4 o1 = *(float4*)(op + 4);
        o0.x = o0.x * bf2f((u16)(mb0.x & 0xffff)) + bf2f((u16)(mb0.x >> 16));
        o0.y = o0.y * bf2f((u16)(mb0.y & 0xffff)) + bf2f((u16)(mb0.y >> 16));
        o0.z = o0.z * bf2f((u16)(mb0.z & 0xffff)) + bf2f((u16)(mb0.z >> 16));
        o0.w = o0.w * bf2f((u16)(mb0.w & 0xffff)) + bf2f((u16)(mb0.w >> 16));
        o1.x = o1.x * bf2f((u16)(mb1.x & 0xffff)) + bf2f((u16)(mb1.x >> 16));
        o1.y = o1.y * bf2f((u16)(mb1.y & 0xffff)) + bf2f((u16)(mb1.y >> 16));
        o1.z = o1.z * bf2f((u16)(mb1.z & 0xffff)) + bf2f((u16)(mb1.z >> 16));
        o1.w = o1.w * bf2f((u16)(mb1.w & 0xffff)) + bf2f((u16)(mb1.w >> 16));
        *(float4*)op = o0;
        *(float4*)(op + 4) = o1;
      }
      __syncthreads();
    }
  }
}

// ---------------------------------------------------------------------------
extern "C" void kernel_launch(void* const* d_in, const int* in_sizes, int n_in,
                              void* d_out, int out_size, void* d_ws, size_t ws_size,
                              hipStream_t stream) {
  const float* x        = (const float*)d_in[0];
  const float* gs       = (const float*)d_in[1];
  const float* cond_gw  = (const float*)d_in[2];
  const float* cond_gb  = (const float*)d_in[3];
  const float* cond_bw  = (const float*)d_in[4];
  const float* cond_bb  = (const float*)d_in[5];
  const float* td       = (const float*)d_in[6];
  const float* Wk       = (const float*)d_in[7];
  const float* Wv       = (const float*)d_in[8];
  const float* Wr       = (const float*)d_in[9];
  const float* Wo       = (const float*)d_in[10];
  const float* ln_g     = (const float*)d_in[11];
  const float* ln_b     = (const float*)d_in[12];
  const float* gp_w     = (const float*)d_in[13];
  const float* gp_b     = (const float*)d_in[14];
  const float* bp_w     = (const float*)d_in[15];
  const float* bp_b     = (const float*)d_in[16];
  float* outp = (float*)d_out;

  char* w = (char*)d_ws;
  float* gamma = (float*)w; w += 4096;
  float* beta  = (float*)w; w += 4096;
  u16* wbf     = (u16*)w;   w += 6 * 2 * 16384 * sizeof(u16);     // 384 KB
  u16* xn      = (u16*)w;   w += (size_t)MM * 128 * sizeof(u16);  // 32 MB
  float* Sbuf  = (float*)w; w += NCH * 1024 * sizeof(float);      // 512 KB
  float* ibuf  = (float*)w; w += NCH * 1024 * sizeof(float);      // 512 KB

  film_kernel<<<4, 256, 0, stream>>>(gs, cond_gw, cond_gb, cond_bw, cond_bb, gamma, beta);
  convert_kernel<<<768, 256, 0, stream>>>(Wk, Wv, Wr, Wo, gp_w, bp_w, wbf);

  for (int blk = 0; blk < 2; ++blk) {
    const u16* bWk = wbf + 0 * 32768 + blk * 16384;
    const u16* bWv = wbf + 1 * 32768 + blk * 16384;
    const u16* bWr = wbf + 2 * 32768 + blk * 16384;
    const u16* bWo = wbf + 3 * 32768 + blk * 16384;
    const u16* bGp = wbf + 4 * 32768 + blk * 16384;
    const u16* bBp = wbf + 5 * 32768 + blk * 16384;
    const float* tdi = td + blk * 128;

    if (blk == 0)
      prep_kernel<1><<<2048, 256, 0, stream>>>(x, gamma, beta, ln_g, ln_b, outp, xn);
    else
      prep_kernel<0><<<2048, 256, 0, stream>>>(outp, nullptr, nullptr, ln_g + 128,
                                               ln_b + 128, nullptr, xn);

    gemm_S_kernel<<<1024, 256, 0, stream>>>(xn, bWk, tdi, Sbuf);
    scan2_kernel<<<256, 256, 0, stream>>>(Sbuf, tdi, ibuf);
    tail_kernel<<<1024, 512, 0, stream>>>(xn, ibuf, tdi, bWk, bWv, bWr,
                                          bWo, bGp, bBp, gp_b + blk * 128,
                                          bp_b + blk * 128, outp);
  }
}

// Round 5
// 707.623 us; speedup vs baseline: 1.7322x; 1.7322x over previous
//
#include <hip/hip_runtime.h>
#include <hip/hip_bf16.h>

// Problem constants
#define BB 8
#define CC 128
#define NN 16384            // 128*128 tokens per batch
#define MM (BB * NN)        // 131072
#define NCH 128             // scan chunks per batch-row
#define CLN 128             // chunk length == GEMM tile M
#define PADT 66             // padded token stride for K/V/R LDS rows (u16)

typedef __attribute__((ext_vector_type(8))) short short8;   // 8 x bf16 (4 VGPRs)
typedef __attribute__((ext_vector_type(4))) float floatx4;  // MFMA accumulator
typedef unsigned short u16;
typedef unsigned int u32;

__device__ __forceinline__ float bf2f(u16 h) {
  u32 u = ((u32)h) << 16;
  return __builtin_bit_cast(float, u);
}
__device__ __forceinline__ u16 f2bf(float f) {
  u32 u = __builtin_bit_cast(u32, f);
  u32 r = u + 0x7FFFu + ((u >> 16) & 1u);   // round-to-nearest-even
  return (u16)(r >> 16);
}

// ---------------------------------------------------------------------------
// FiLM params: gamma[b,c] = gs[b,:]·cond_gw[c,:] + cond_gb[c]; beta likewise.
__global__ void film_kernel(const float* __restrict__ gs, const float* __restrict__ gw,
                            const float* __restrict__ gb, const float* __restrict__ bw,
                            const float* __restrict__ bb, float* __restrict__ gamma,
                            float* __restrict__ beta) {
  int idx = blockIdx.x * 256 + threadIdx.x;   // 0..1023
  int b = idx >> 7, c = idx & 127;
  float sg = 0.f, sb = 0.f;
  for (int j = 0; j < 128; ++j) {
    float g = gs[b * 128 + j];
    sg += g * gw[c * 128 + j];
    sb += g * bw[c * 128 + j];
  }
  gamma[idx] = sg + gb[c];
  beta[idx] = sb + bb[c];
}

// ---------------------------------------------------------------------------
// Convert all 6 weight tensors (each (2,128,128) f32) to bf16, packed
// [which][block][o][c] at dst + which*32768.
__global__ void convert_kernel(const float* __restrict__ Wk, const float* __restrict__ Wv,
                               const float* __restrict__ Wr, const float* __restrict__ Wo,
                               const float* __restrict__ gp, const float* __restrict__ bp,
                               u16* __restrict__ dst) {
  int idx = blockIdx.x * 256 + threadIdx.x;   // 0..196607
  int which = idx >> 15;
  int off = idx & 32767;
  const float* s;
  switch (which) {
    case 0: s = Wk; break; case 1: s = Wv; break; case 2: s = Wr; break;
    case 3: s = Wo; break; case 4: s = gp; break; default: s = bp; break;
  }
  dst[idx] = f2bf(s[off]);
}

// ---------------------------------------------------------------------------
// Prep: (UPS=1) bilinear 2x upsample + write x_up to out(BCHW) + FiLM + LN -> xn bf16
//       (UPS=0) read out(BCHW) + LN -> xn bf16
template <int UPS>
__global__ __launch_bounds__(256) void prep_kernel(
    const float* __restrict__ src, const float* __restrict__ gamma,
    const float* __restrict__ beta, const float* __restrict__ lng,
    const float* __restrict__ lnb, float* __restrict__ outp, u16* __restrict__ xn) {
  __shared__ float tile[64][129];
  __shared__ float smu[64], srs[64];
  int bidx = blockIdx.x;              // 0..2047
  int half = bidx & 1;
  int ho = (bidx >> 1) & 127;
  int b = bidx >> 8;
  int wo0 = half * 64;
  int tid = threadIdx.x;
  int tk = tid & 63;
  int wo = wo0 + tk;
  int c0 = tid >> 6;                  // 0..3
  int j0 = 0, j1 = 0, i0 = 0, i1 = 0;
  float wy0 = 0.f, wy1 = 0.f, wx0 = 0.f, wx1 = 0.f;
  if (UPS) {
    int jj = ho >> 1;
    if ((ho & 1) == 0) { j0 = jj > 0 ? jj - 1 : 0; j1 = jj; wy0 = 0.25f; wy1 = 0.75f; }
    else               { j0 = jj; j1 = jj < 63 ? jj + 1 : 63; wy0 = 0.75f; wy1 = 0.25f; }
    int ii = wo >> 1;
    if ((wo & 1) == 0) { i0 = ii > 0 ? ii - 1 : 0; i1 = ii; wx0 = 0.25f; wx1 = 0.75f; }
    else               { i0 = ii; i1 = ii < 63 ? ii + 1 : 63; wx0 = 0.75f; wx1 = 0.25f; }
  }
  for (int it = 0; it < 32; ++it) {
    int c = it * 4 + c0;
    float v;
    if (UPS) {
      const float* xp = src + ((size_t)(b * 128 + c)) * 4096;
      v = wy0 * (wx0 * xp[j0 * 64 + i0] + wx1 * xp[j0 * 64 + i1]) +
          wy1 * (wx0 * xp[j1 * 64 + i0] + wx1 * xp[j1 * 64 + i1]);
      outp[((size_t)(b * 128 + c)) * 16384 + ho * 128 + wo] = v;
      v = v * (1.f + gamma[b * 128 + c]) + beta[b * 128 + c];
    } else {
      v = src[((size_t)(b * 128 + c)) * 16384 + ho * 128 + wo];
    }
    tile[tk][c] = v;
  }
  __syncthreads();
  {
    int token = tid >> 2, q = tid & 3;
    float s = 0.f, s2 = 0.f;
    for (int j = 0; j < 32; ++j) { float v = tile[token][q * 32 + j]; s += v; s2 += v * v; }
    s += __shfl_xor(s, 1); s2 += __shfl_xor(s2, 1);
    s += __shfl_xor(s, 2); s2 += __shfl_xor(s2, 2);
    if (q == 0) {
      float mu = s * 0.0078125f;
      float var = s2 * 0.0078125f - mu * mu;
      smu[token] = mu;
      srs[token] = rsqrtf(var + 1e-5f);
    }
  }
  __syncthreads();
  size_t base = ((size_t)b * 16384 + ho * 128 + wo0) * 128;
  for (int it = 0; it < 32; ++it) {
    int idx = it * 256 + tid;
    int token = idx >> 7, c = idx & 127;
    float v = (tile[token][c] - smu[token]) * srs[token] * lng[c] + lnb[c];
    xn[base + idx] = f2bf(v);
  }
}

// ---------------------------------------------------------------------------
// gemm_S: k-GEMM only, fused decay-weighted chunk sum -> Sbuf. No other output.
__global__ __launch_bounds__(256) void gemm_S_kernel(
    const u16* __restrict__ A, const u16* __restrict__ W0,
    const float* __restrict__ td, float* __restrict__ Sbuf) {
  __shared__ u16 Alds[128 * 128];
  __shared__ u16 Wlds[128 * 128];
  __shared__ float Sred[512];         // [wave][c]
  int tid = threadIdx.x;
  int wave = tid >> 6, lane = tid & 63;
  int l15 = lane & 15, l4 = lane >> 4;
  size_t row0 = (size_t)blockIdx.x * 128;
#pragma unroll
  for (int it = 0; it < 8; ++it) {
    int idx = it * 256 + tid;
    int rr = idx >> 4, s = idx & 15;
    uint4 d = *(const uint4*)(A + (row0 + rr) * 128 + s * 8);
    *(uint4*)(&Alds[rr * 128 + ((s ^ (rr & 15)) << 3)]) = d;
  }
#pragma unroll
  for (int it = 0; it < 8; ++it) {
    int idx = it * 256 + tid;
    int rr = idx >> 4, s = idx & 15;
    uint4 d = *(const uint4*)(W0 + rr * 128 + s * 8);
    *(uint4*)(&Wlds[rr * 128 + ((s ^ (rr & 15)) << 3)]) = d;
  }
  __syncthreads();
  floatx4 acc[2][8];
#pragma unroll
  for (int mi = 0; mi < 2; ++mi)
#pragma unroll
    for (int ni = 0; ni < 8; ++ni) acc[mi][ni] = (floatx4){0.f, 0.f, 0.f, 0.f};
#pragma unroll
  for (int kk = 0; kk < 4; ++kk) {
    int seg = kk * 4 + l4;
    short8 a0 = *(const short8*)(&Alds[(wave * 32 + l15) * 128 + ((seg ^ l15) << 3)]);
    short8 a1 = *(const short8*)(&Alds[(wave * 32 + 16 + l15) * 128 + ((seg ^ l15) << 3)]);
#pragma unroll
    for (int ni = 0; ni < 8; ++ni) {
      short8 bfr = *(const short8*)(&Wlds[(ni * 16 + l15) * 128 + ((seg ^ l15) << 3)]);
      acc[0][ni] = __builtin_amdgcn_mfma_f32_16x16x32_bf16(a0, bfr, acc[0][ni], 0, 0, 0);
      acc[1][ni] = __builtin_amdgcn_mfma_f32_16x16x32_bf16(a1, bfr, acc[1][ni], 0, 0, 0);
    }
  }
  // S_c = sum_tau d_c^{127-tau} k[tau][c]; tau = wave*32 + mi*16 + l4*4 + j
  int T0 = wave * 32 + l4 * 4;
#pragma unroll
  for (int ni = 0; ni < 8; ++ni) {
    int c = ni * 16 + l15;
    float a = fmaxf(td[c], 0.f);
    float E = __expf(-a * (float)(127 - T0));   // d^{127-T0}
    float r1 = __expf(a);                        // d^{-1}
    float r16 = __expf(a * 16.f);
    float w = E, sum;
    sum  = w * acc[0][ni][0]; w *= r1;
    sum += w * acc[0][ni][1]; w *= r1;
    sum += w * acc[0][ni][2]; w *= r1;
    sum += w * acc[0][ni][3];
    w = E * r16;
    sum += w * acc[1][ni][0]; w *= r1;
    sum += w * acc[1][ni][1]; w *= r1;
    sum += w * acc[1][ni][2]; w *= r1;
    sum += w * acc[1][ni][3];
    sum += __shfl_xor(sum, 16);
    sum += __shfl_xor(sum, 32);
    if (l4 == 0) Sred[wave * 128 + c] = sum;
  }
  __syncthreads();
  if (tid < 128) {
    float s = Sred[tid] + Sred[128 + tid] + Sred[256 + tid] + Sred[384 + tid];
    Sbuf[(blockIdx.x & 127) * 1024 + (blockIdx.x >> 7) * 128 + tid] = s;
  }
}

// ---------------------------------------------------------------------------
// Scan phase 2: per (b,c) scan over 128 chunks; one wave, 2 chunks per lane.
__global__ __launch_bounds__(256) void scan2_kernel(const float* __restrict__ S,
                                                    const float* __restrict__ td,
                                                    float* __restrict__ init) {
  int wave = threadIdx.x >> 6, lane = threadIdx.x & 63;
  int bc = blockIdx.x * 4 + wave;   // 0..1023
  int c = bc & 127;
  float a1 = __expf(-fmaxf(td[c], 0.f) * 128.f);   // decay^CLN
  float s0 = S[(2 * lane) * 1024 + bc];
  float s1 = S[(2 * lane + 1) * 1024 + bc];
  float s = s1 + a1 * s0;   // pair-combined segment sum
  float a = a1 * a1;
  for (int off = 1; off < 64; off <<= 1) {
    float ss = __shfl_up(s, off);
    float aa = __shfl_up(a, off);
    if (lane >= off) { s = s + a * ss; a = a * aa; }
  }
  float e = __shfl_up(s, 1);          // exclusive over pairs
  if (lane == 0) e = 0.f;
  init[(2 * lane) * 1024 + bc] = e;
  init[(2 * lane + 1) * 1024 + bc] = a1 * e + s0;
}

// ---------------------------------------------------------------------------
// Mega-tail v3: per (b, chunk of 128 tokens), two 64-token halves.
// Recomputes k,v,r from xn; k/v/r staged bf16 in padded LDS rows (low VGPR);
// scan + y fused; then Wo / gp / bp GEMMs and blend RMW. ~68 KB LDS.
__global__ __launch_bounds__(512, 2) void tail_kernel(
    const u16* __restrict__ xn, const float* __restrict__ init,
    const float* __restrict__ td,
    const u16* __restrict__ Wk, const u16* __restrict__ Wv, const u16* __restrict__ Wr,
    const u16* __restrict__ Wo, const u16* __restrict__ Wg, const u16* __restrict__ Wb,
    const float* __restrict__ gpb, const float* __restrict__ bpb,
    float* __restrict__ outp) {
  __shared__ u16 XN[8192];            // 16 KB: xn tile / Y [tok][c] swz / MB u32[64][64]
  __shared__ u16 KL[128 * PADT];      // 16.9 KB: k rows [c][t] (pad 66) / later T2
  __shared__ u16 VL[128 * PADT];      // 16.9 KB: v rows
  __shared__ u16 RL[128 * PADT];      // 16.9 KB: r rows (pre-sigmoid)
  __shared__ float SC[512];           // sub-chunk local sums [sub][c]
  __shared__ float CAR[128];          // cross-half state carry

  u16* T2 = KL;
  u32* MB = (u32*)XN;

  int tid = threadIdx.x;
  int wave = tid >> 6, lane = tid & 63;
  int l15 = lane & 15, l4 = lane >> 4;
  int b = blockIdx.x >> 7;
  int chunk = blockIdx.x & 127;
  int tg = wave >> 1;                 // token group 0..3 (16 tokens)
  int ch = wave & 1;                  // channel half for kvr GEMMs
  int sc = tid & 127;                 // scan channel
  int sub = tid >> 7;                 // scan sub-chunk 0..3 (16 tokens)
  float sa_ = fmaxf(td[sc], 0.f);
  float sd_ = __expf(-sa_);
  float sd16_ = __expf(-sa_ * 16.f);

  for (int hf = 0; hf < 2; ++hf) {
    size_t gb = (size_t)b * 16384 + (size_t)chunk * 128 + hf * 64;

    // ---- 1: stage xn half-tile (64 tok x 128 c, XOR swz) ----
#pragma unroll
    for (int it = 0; it < 2; ++it) {
      int idx = it * 512 + tid;
      int rr = idx >> 4, s = idx & 15;
      uint4 d = *(const uint4*)(xn + (gb + rr) * 128 + s * 8);
      *(uint4*)(&XN[rr * 128 + ((s ^ (rr & 15)) << 3)]) = d;
    }
    __syncthreads();

    // ---- 2: k,v,r GEMMs -> padded LDS rows ----
    short8 afr[4];
#pragma unroll
    for (int kk = 0; kk < 4; ++kk)
      afr[kk] = *(const short8*)(&XN[(tg * 16 + l15) * 128 + (((kk * 4 + l4) ^ l15) << 3)]);
    {
      const u16* Ws[3] = {Wk, Wv, Wr};
      u16* Ls[3] = {KL, VL, RL};
#pragma unroll
      for (int wsi = 0; wsi < 3; ++wsi) {
        floatx4 ac[4];
#pragma unroll
        for (int ni = 0; ni < 4; ++ni) ac[ni] = (floatx4){0.f, 0.f, 0.f, 0.f};
#pragma unroll
        for (int kk = 0; kk < 4; ++kk) {
#pragma unroll
          for (int ni = 0; ni < 4; ++ni) {
            short8 bw = *(const short8*)(Ws[wsi] + (ch * 64 + ni * 16 + l15) * 128 +
                                         kk * 32 + l4 * 8);
            ac[ni] = __builtin_amdgcn_mfma_f32_16x16x32_bf16(afr[kk], bw, ac[ni], 0, 0, 0);
          }
        }
        u16* L = Ls[wsi];
#pragma unroll
        for (int ni = 0; ni < 4; ++ni) {
          int c = ch * 64 + ni * 16 + l15;
          int tb = tg * 16 + l4 * 4;
          u32 p0 = (u32)f2bf(ac[ni][0]) | ((u32)f2bf(ac[ni][1]) << 16);
          u32 p1 = (u32)f2bf(ac[ni][2]) | ((u32)f2bf(ac[ni][3]) << 16);
          *(u32*)(&L[c * PADT + tb]) = p0;
          *(u32*)(&L[c * PADT + tb + 2]) = p1;
        }
      }
    }
    float st0 = (hf == 0) ? init[chunk * 1024 + b * 128 + sc] : CAR[sc];
    __syncthreads();

    // ---- 3: scan local sums per (c, sub of 16) ----
    {
      float ls = 0.f;
#pragma unroll
      for (int i = 0; i < 16; i += 2) {
        u32 kk2 = *(const u32*)(&KL[sc * PADT + sub * 16 + i]);
        ls = ls * sd_ + bf2f((u16)(kk2 & 0xffff));
        ls = ls * sd_ + bf2f((u16)(kk2 >> 16));
      }
      SC[sub * 128 + sc] = ls;
    }
    __syncthreads();

    // ---- 4: replay + y = sigmoid(r)*(s+v) -> Y ([tok][c] swz over XN) ----
    {
      float st = st0;
#pragma unroll
      for (int j = 0; j < 3; ++j)
        if (j < sub) st = st * sd16_ + SC[j * 128 + sc];
      int chi = sc >> 3, clo = sc & 7;
#pragma unroll
      for (int i = 0; i < 16; i += 2) {
        int t = sub * 16 + i;
        u32 kk2 = *(const u32*)(&KL[sc * PADT + t]);
        u32 vv2 = *(const u32*)(&VL[sc * PADT + t]);
        u32 rr2 = *(const u32*)(&RL[sc * PADT + t]);
        st = st * sd_ + bf2f((u16)(kk2 & 0xffff));
        float r0 = bf2f((u16)(rr2 & 0xffff));
        float y0 = (st + bf2f((u16)(vv2 & 0xffff))) / (1.f + __expf(-r0));
        XN[t * 128 + (((chi ^ (t & 15)) << 3) | clo)] = f2bf(y0);
        st = st * sd_ + bf2f((u16)(kk2 >> 16));
        float r1 = bf2f((u16)(rr2 >> 16));
        float y1 = (st + bf2f((u16)(vv2 >> 16))) / (1.f + __expf(-r1));
        XN[(t + 1) * 128 + (((chi ^ ((t + 1) & 15)) << 3) | clo)] = f2bf(y1);
      }
      if (sub == 3) CAR[sc] = st;
    }
    __syncthreads();

    // ---- 5: GEMM1 t = Wo . y^T -> T2 (= KL region, [tok][o] swz) ----
    int ob1 = wave * 16;
    {
      floatx4 a1[4];
#pragma unroll
      for (int ni = 0; ni < 4; ++ni) a1[ni] = (floatx4){0.f, 0.f, 0.f, 0.f};
#pragma unroll
      for (int kk = 0; kk < 4; ++kk) {
        short8 wof = *(const short8*)(Wo + (ob1 + l15) * 128 + kk * 32 + l4 * 8);
#pragma unroll
        for (int ni = 0; ni < 4; ++ni) {
          short8 yf = *(const short8*)(&XN[(ni * 16 + l15) * 128 + (((kk * 4 + l4) ^ l15) << 3)]);
          a1[ni] = __builtin_amdgcn_mfma_f32_16x16x32_bf16(wof, yf, a1[ni], 0, 0, 0);
        }
      }
#pragma unroll
      for (int ni = 0; ni < 4; ++ni) {
        int tok = ni * 16 + l15;
#pragma unroll
        for (int j = 0; j < 4; j += 2) {
          int o = ob1 + l4 * 4 + j;
          u32 pack = (u32)f2bf(a1[ni][j]) | ((u32)f2bf(a1[ni][j + 1]) << 16);
          int pos = tok * 128 + ((((o >> 3) ^ (tok & 15)) << 3) | (o & 7));
          *(u32*)(&T2[pos]) = pack;
        }
      }
    }
    __syncthreads();

    // ---- 6: GEMM2 g/bt = Wg/Wb . t^T ----
    floatx4 ag[4], ab[4];
#pragma unroll
    for (int ni = 0; ni < 4; ++ni) {
      ag[ni] = (floatx4){0.f, 0.f, 0.f, 0.f};
      ab[ni] = (floatx4){0.f, 0.f, 0.f, 0.f};
    }
#pragma unroll
    for (int kk = 0; kk < 4; ++kk) {
      short8 wgf = *(const short8*)(Wg + (ob1 + l15) * 128 + kk * 32 + l4 * 8);
      short8 wbf = *(const short8*)(Wb + (ob1 + l15) * 128 + kk * 32 + l4 * 8);
#pragma unroll
      for (int ni = 0; ni < 4; ++ni) {
        short8 tf = *(const short8*)(&T2[(ni * 16 + l15) * 128 + (((kk * 4 + l4) ^ l15) << 3)]);
        ag[ni] = __builtin_amdgcn_mfma_f32_16x16x32_bf16(wgf, tf, ag[ni], 0, 0, 0);
        ab[ni] = __builtin_amdgcn_mfma_f32_16x16x32_bf16(wbf, tf, ab[ni], 0, 0, 0);
      }
    }
    __syncthreads();

    // ---- 7: epilogue, two o-halves through MB (= XN region) ----
#pragma unroll
    for (int h = 0; h < 2; ++h) {
      if ((wave >> 2) == h) {
        int orel0 = (wave & 3) * 16;
#pragma unroll
        for (int ni = 0; ni < 4; ++ni) {
          int tok = ni * 16 + l15;
#pragma unroll
          for (int j = 0; j < 4; ++j) {
            int orel = orel0 + l4 * 4 + j;
            int o = h * 64 + orel;
            float g = ag[ni][j] + gpb[o];
            float t1 = __expf(2.f * g);
            float m = 2.f - 2.f / (t1 + 1.f);          // 1 + tanh(g), inf-safe
            float bt = ab[ni][j] + bpb[o];
            MB[orel * 64 + ((((tok >> 3) ^ (orel & 7)) << 3) | (tok & 7))] =
                (u32)f2bf(m) | ((u32)f2bf(bt) << 16);
          }
        }
      }
      __syncthreads();
      {
        int orel = tid >> 3, seg = tid & 7;
        int sp = ((seg ^ (orel & 7)) << 3);
        uint4 mb0 = *(const uint4*)(&MB[orel * 64 + sp]);
        uint4 mb1 = *(const uint4*)(&MB[orel * 64 + sp + 4]);
        float* op = outp + ((size_t)(b * 128 + h * 64 + orel)) * 16384 +
                    chunk * 128 + hf * 64 + seg * 8;
        float4 o0 = *(float4*)op;
        float4 o1 = *(float4*)(op + 4);
        o0.x = o0.x * bf2f((u16)(mb0.x & 0xffff)) + bf2f((u16)(mb0.x >> 16));
        o0.y = o0.y * bf2f((u16)(mb0.y & 0xffff)) + bf2f((u16)(mb0.y >> 16));
        o0.z = o0.z * bf2f((u16)(mb0.z & 0xffff)) + bf2f((u16)(mb0.z >> 16));
        o0.w = o0.w * bf2f((u16)(mb0.w & 0xffff)) + bf2f((u16)(mb0.w >> 16));
        o1.x = o1.x * bf2f((u16)(mb1.x & 0xffff)) + bf2f((u16)(mb1.x >> 16));
        o1.y = o1.y * bf2f((u16)(mb1.y & 0xffff)) + bf2f((u16)(mb1.y >> 16));
        o1.z = o1.z * bf2f((u16)(mb1.z & 0xffff)) + bf2f((u16)(mb1.z >> 16));
        o1.w = o1.w * bf2f((u16)(mb1.w & 0xffff)) + bf2f((u16)(mb1.w >> 16));
        *(float4*)op = o0;
        *(float4*)(op + 4) = o1;
      }
      __syncthreads();
    }
  }
}

// ---------------------------------------------------------------------------
extern "C" void kernel_launch(void* const* d_in, const int* in_sizes, int n_in,
                              void* d_out, int out_size, void* d_ws, size_t ws_size,
                              hipStream_t stream) {
  const float* x        = (const float*)d_in[0];
  const float* gs       = (const float*)d_in[1];
  const float* cond_gw  = (const float*)d_in[2];
  const float* cond_gb  = (const float*)d_in[3];
  const float* cond_bw  = (const float*)d_in[4];
  const float* cond_bb  = (const float*)d_in[5];
  const float* td       = (const float*)d_in[6];
  const float* Wk       = (const float*)d_in[7];
  const float* Wv       = (const float*)d_in[8];
  const float* Wr       = (const float*)d_in[9];
  const float* Wo       = (const float*)d_in[10];
  const float* ln_g     = (const float*)d_in[11];
  const float* ln_b     = (const float*)d_in[12];
  const float* gp_w     = (const float*)d_in[13];
  const float* gp_b     = (const float*)d_in[14];
  const float* bp_w     = (const float*)d_in[15];
  const float* bp_b     = (const float*)d_in[16];
  float* outp = (float*)d_out;

  char* w = (char*)d_ws;
  float* gamma = (float*)w; w += 4096;
  float* beta  = (float*)w; w += 4096;
  u16* wbf     = (u16*)w;   w += 6 * 2 * 16384 * sizeof(u16);     // 384 KB
  u16* xn      = (u16*)w;   w += (size_t)MM * 128 * sizeof(u16);  // 32 MB
  float* Sbuf  = (float*)w; w += NCH * 1024 * sizeof(float);      // 512 KB
  float* ibuf  = (float*)w; w += NCH * 1024 * sizeof(float);      // 512 KB

  film_kernel<<<4, 256, 0, stream>>>(gs, cond_gw, cond_gb, cond_bw, cond_bb, gamma, beta);
  convert_kernel<<<768, 256, 0, stream>>>(Wk, Wv, Wr, Wo, gp_w, bp_w, wbf);

  for (int blk = 0; blk < 2; ++blk) {
    const u16* bWk = wbf + 0 * 32768 + blk * 16384;
    const u16* bWv = wbf + 1 * 32768 + blk * 16384;
    const u16* bWr = wbf + 2 * 32768 + blk * 16384;
    const u16* bWo = wbf + 3 * 32768 + blk * 16384;
    const u16* bGp = wbf + 4 * 32768 + blk * 16384;
    const u16* bBp = wbf + 5 * 32768 + blk * 16384;
    const float* tdi = td + blk * 128;

    if (blk == 0)
      prep_kernel<1><<<2048, 256, 0, stream>>>(x, gamma, beta, ln_g, ln_b, outp, xn);
    else
      prep_kernel<0><<<2048, 256, 0, stream>>>(outp, nullptr, nullptr, ln_g + 128,
                                               ln_b + 128, nullptr, xn);

    gemm_S_kernel<<<1024, 256, 0, stream>>>(xn, bWk, tdi, Sbuf);
    scan2_kernel<<<256, 256, 0, stream>>>(Sbuf, tdi, ibuf);
    tail_kernel<<<1024, 512, 0, stream>>>(xn, ibuf, tdi, bWk, bWv, bWr,
                                          bWo, bGp, bBp, gp_b + blk * 128,
                                          bp_b + blk * 128, outp);
  }
}

// Round 6
// 268.938 us; speedup vs baseline: 4.5578x; 2.6312x over previous
//
#include <hip/hip_runtime.h>
#include <hip/hip_bf16.h>

// Problem constants
#define BB 8
#define CC 128
#define NN 16384            // 128*128 tokens per batch
#define MM (BB * NN)        // 131072
#define NCH 128             // scan chunks per batch-row
#define CLN 128             // chunk length == GEMM tile M

typedef __attribute__((ext_vector_type(8))) short short8;   // 8 x bf16 (4 VGPRs)
typedef __attribute__((ext_vector_type(4))) float floatx4;  // MFMA accumulator
typedef unsigned short u16;
typedef unsigned int u32;

__device__ __forceinline__ float bf2f(u16 h) {
  u32 u = ((u32)h) << 16;
  return __builtin_bit_cast(float, u);
}
__device__ __forceinline__ u16 f2bf(float f) {
  u32 u = __builtin_bit_cast(u32, f);
  u32 r = u + 0x7FFFu + ((u >> 16) & 1u);   // round-to-nearest-even
  return (u16)(r >> 16);
}

// ---------------------------------------------------------------------------
// FiLM params: gamma[b,c] = gs[b,:]·cond_gw[c,:] + cond_gb[c]; beta likewise.
__global__ void film_kernel(const float* __restrict__ gs, const float* __restrict__ gw,
                            const float* __restrict__ gb, const float* __restrict__ bw,
                            const float* __restrict__ bb, float* __restrict__ gamma,
                            float* __restrict__ beta) {
  int idx = blockIdx.x * 256 + threadIdx.x;   // 0..1023
  int b = idx >> 7, c = idx & 127;
  float sg = 0.f, sb = 0.f;
  for (int j = 0; j < 128; ++j) {
    float g = gs[b * 128 + j];
    sg += g * gw[c * 128 + j];
    sb += g * bw[c * 128 + j];
  }
  gamma[idx] = sg + gb[c];
  beta[idx] = sb + bb[c];
}

// ---------------------------------------------------------------------------
// Convert all 6 weight tensors (each (2,128,128) f32) to bf16, packed
// [which][block][o][c] at dst + which*32768.
__global__ void convert_kernel(const float* __restrict__ Wk, const float* __restrict__ Wv,
                               const float* __restrict__ Wr, const float* __restrict__ Wo,
                               const float* __restrict__ gp, const float* __restrict__ bp,
                               u16* __restrict__ dst) {
  int idx = blockIdx.x * 256 + threadIdx.x;   // 0..196607
  int which = idx >> 15;
  int off = idx & 32767;
  const float* s;
  switch (which) {
    case 0: s = Wk; break; case 1: s = Wv; break; case 2: s = Wr; break;
    case 3: s = Wo; break; case 4: s = gp; break; default: s = bp; break;
  }
  dst[idx] = f2bf(s[off]);
}

// ---------------------------------------------------------------------------
// Prep: (UPS=1) bilinear 2x upsample + write x_up to out(BCHW) + FiLM + LN -> xn bf16
//       (UPS=0) read out(BCHW) + LN -> xn bf16
template <int UPS>
__global__ __launch_bounds__(256) void prep_kernel(
    const float* __restrict__ src, const float* __restrict__ gamma,
    const float* __restrict__ beta, const float* __restrict__ lng,
    const float* __restrict__ lnb, float* __restrict__ outp, u16* __restrict__ xn) {
  __shared__ float tile[64][129];
  __shared__ float smu[64], srs[64];
  int bidx = blockIdx.x;              // 0..2047
  int half = bidx & 1;
  int ho = (bidx >> 1) & 127;
  int b = bidx >> 8;
  int wo0 = half * 64;
  int tid = threadIdx.x;
  int tk = tid & 63;
  int wo = wo0 + tk;
  int c0 = tid >> 6;                  // 0..3
  int j0 = 0, j1 = 0, i0 = 0, i1 = 0;
  float wy0 = 0.f, wy1 = 0.f, wx0 = 0.f, wx1 = 0.f;
  if (UPS) {
    int jj = ho >> 1;
    if ((ho & 1) == 0) { j0 = jj > 0 ? jj - 1 : 0; j1 = jj; wy0 = 0.25f; wy1 = 0.75f; }
    else               { j0 = jj; j1 = jj < 63 ? jj + 1 : 63; wy0 = 0.75f; wy1 = 0.25f; }
    int ii = wo >> 1;
    if ((wo & 1) == 0) { i0 = ii > 0 ? ii - 1 : 0; i1 = ii; wx0 = 0.25f; wx1 = 0.75f; }
    else               { i0 = ii; i1 = ii < 63 ? ii + 1 : 63; wx0 = 0.75f; wx1 = 0.25f; }
  }
  for (int it = 0; it < 32; ++it) {
    int c = it * 4 + c0;
    float v;
    if (UPS) {
      const float* xp = src + ((size_t)(b * 128 + c)) * 4096;
      v = wy0 * (wx0 * xp[j0 * 64 + i0] + wx1 * xp[j0 * 64 + i1]) +
          wy1 * (wx0 * xp[j1 * 64 + i0] + wx1 * xp[j1 * 64 + i1]);
      outp[((size_t)(b * 128 + c)) * 16384 + ho * 128 + wo] = v;
      v = v * (1.f + gamma[b * 128 + c]) + beta[b * 128 + c];
    } else {
      v = src[((size_t)(b * 128 + c)) * 16384 + ho * 128 + wo];
    }
    tile[tk][c] = v;
  }
  __syncthreads();
  {
    int token = tid >> 2, q = tid & 3;
    float s = 0.f, s2 = 0.f;
    for (int j = 0; j < 32; ++j) { float v = tile[token][q * 32 + j]; s += v; s2 += v * v; }
    s += __shfl_xor(s, 1); s2 += __shfl_xor(s2, 1);
    s += __shfl_xor(s, 2); s2 += __shfl_xor(s2, 2);
    if (q == 0) {
      float mu = s * 0.0078125f;
      float var = s2 * 0.0078125f - mu * mu;
      smu[token] = mu;
      srs[token] = rsqrtf(var + 1e-5f);
    }
  }
  __syncthreads();
  size_t base = ((size_t)b * 16384 + ho * 128 + wo0) * 128;
  for (int it = 0; it < 32; ++it) {
    int idx = it * 256 + tid;
    int token = idx >> 7, c = idx & 127;
    float v = (tile[token][c] - smu[token]) * srs[token] * lng[c] + lnb[c];
    xn[base + idx] = f2bf(v);
  }
}

// ---------------------------------------------------------------------------
// gemm_y: v,r,k GEMMs + sigmoid + in-register chunk-local scan.
// Outputs: y_local = sig(r)*(v + local_scan(k))  (bf16, coalesced via LDS)
//          rd      = sig(r)*d^{t+1}              (bf16)
//          Sbuf    = chunk total sum d^{127-tau} k_tau (f32)
__global__ __launch_bounds__(256, 2) void gemm_y_kernel(
    const u16* __restrict__ A, const u16* __restrict__ Wv_, const u16* __restrict__ Wr_,
    const u16* __restrict__ Wk_, const float* __restrict__ td,
    u16* __restrict__ outY, u16* __restrict__ outRD, float* __restrict__ Sbuf) {
  __shared__ u16 Alds[128 * 128];
  __shared__ u16 Wlds[128 * 128];
  __shared__ float SWT[512];          // per-wave 32-token inclusive totals [wave][c]
  int tid = threadIdx.x;
  int wave = tid >> 6, lane = tid & 63;
  int l15 = lane & 15, l4 = lane >> 4;
  size_t row0 = (size_t)blockIdx.x * 128;

  // stage A (xn tile) + first weight (Wv)
#pragma unroll
  for (int it = 0; it < 8; ++it) {
    int idx = it * 256 + tid;
    int rr = idx >> 4, s = idx & 15;
    uint4 d = *(const uint4*)(A + (row0 + rr) * 128 + s * 8);
    *(uint4*)(&Alds[rr * 128 + ((s ^ (rr & 15)) << 3)]) = d;
  }
#pragma unroll
  for (int it = 0; it < 8; ++it) {
    int idx = it * 256 + tid;
    int rr = idx >> 4, s = idx & 15;
    uint4 d = *(const uint4*)(Wv_ + rr * 128 + s * 8);
    *(uint4*)(&Wlds[rr * 128 + ((s ^ (rr & 15)) << 3)]) = d;
  }
  // per-ni channel decay constants
  float av[8], dd[8], d4a[8];
#pragma unroll
  for (int ni = 0; ni < 8; ++ni) {
    float a = fmaxf(td[ni * 16 + l15], 0.f);
    av[ni] = a;
    float d = __expf(-a);
    dd[ni] = d;
    float d2 = d * d;
    d4a[ni] = d2 * d2;
  }
  __syncthreads();

  // ---- v GEMM ----
  floatx4 accv[2][8];
#pragma unroll
  for (int mi = 0; mi < 2; ++mi)
#pragma unroll
    for (int ni = 0; ni < 8; ++ni) accv[mi][ni] = (floatx4){0.f, 0.f, 0.f, 0.f};
#pragma unroll
  for (int kk = 0; kk < 4; ++kk) {
    int seg = kk * 4 + l4;
    short8 a0 = *(const short8*)(&Alds[(wave * 32 + l15) * 128 + ((seg ^ l15) << 3)]);
    short8 a1 = *(const short8*)(&Alds[(wave * 32 + 16 + l15) * 128 + ((seg ^ l15) << 3)]);
#pragma unroll
    for (int ni = 0; ni < 8; ++ni) {
      short8 bfr = *(const short8*)(&Wlds[(ni * 16 + l15) * 128 + ((seg ^ l15) << 3)]);
      accv[0][ni] = __builtin_amdgcn_mfma_f32_16x16x32_bf16(a0, bfr, accv[0][ni], 0, 0, 0);
      accv[1][ni] = __builtin_amdgcn_mfma_f32_16x16x32_bf16(a1, bfr, accv[1][ni], 0, 0, 0);
    }
  }
  __syncthreads();
  // ---- r GEMM ----
#pragma unroll
  for (int it = 0; it < 8; ++it) {
    int idx = it * 256 + tid;
    int rr = idx >> 4, s = idx & 15;
    uint4 d = *(const uint4*)(Wr_ + rr * 128 + s * 8);
    *(uint4*)(&Wlds[rr * 128 + ((s ^ (rr & 15)) << 3)]) = d;
  }
  __syncthreads();
  floatx4 accr[2][8];
#pragma unroll
  for (int mi = 0; mi < 2; ++mi)
#pragma unroll
    for (int ni = 0; ni < 8; ++ni) accr[mi][ni] = (floatx4){0.f, 0.f, 0.f, 0.f};
#pragma unroll
  for (int kk = 0; kk < 4; ++kk) {
    int seg = kk * 4 + l4;
    short8 a0 = *(const short8*)(&Alds[(wave * 32 + l15) * 128 + ((seg ^ l15) << 3)]);
    short8 a1 = *(const short8*)(&Alds[(wave * 32 + 16 + l15) * 128 + ((seg ^ l15) << 3)]);
#pragma unroll
    for (int ni = 0; ni < 8; ++ni) {
      short8 bfr = *(const short8*)(&Wlds[(ni * 16 + l15) * 128 + ((seg ^ l15) << 3)]);
      accr[0][ni] = __builtin_amdgcn_mfma_f32_16x16x32_bf16(a0, bfr, accr[0][ni], 0, 0, 0);
      accr[1][ni] = __builtin_amdgcn_mfma_f32_16x16x32_bf16(a1, bfr, accr[1][ni], 0, 0, 0);
    }
  }
  // sigmoid; write rd; pack r and r*v as bf16 (frees accv/accr)
  u32 rvp[2][8][2], rp[2][8][2];
#pragma unroll
  for (int mi = 0; mi < 2; ++mi) {
#pragma unroll
    for (int ni = 0; ni < 8; ++ni) {
      int c = ni * 16 + l15;
      int T0 = wave * 32 + mi * 16 + l4 * 4;
      float w = __expf(-av[ni] * (float)(T0 + 1));   // d^{T0+1}
      float rs[4], rv[4];
#pragma unroll
      for (int j = 0; j < 4; ++j) {
        float sg = 1.f / (1.f + __expf(-accr[mi][ni][j]));
        rs[j] = sg;
        rv[j] = sg * accv[mi][ni][j];
        outRD[(row0 + T0 + j) * 128 + c] = f2bf(sg * w);
        w *= dd[ni];
      }
      rvp[mi][ni][0] = (u32)f2bf(rv[0]) | ((u32)f2bf(rv[1]) << 16);
      rvp[mi][ni][1] = (u32)f2bf(rv[2]) | ((u32)f2bf(rv[3]) << 16);
      rp[mi][ni][0] = (u32)f2bf(rs[0]) | ((u32)f2bf(rs[1]) << 16);
      rp[mi][ni][1] = (u32)f2bf(rs[2]) | ((u32)f2bf(rs[3]) << 16);
    }
  }
  __syncthreads();
  // ---- k GEMM ----
#pragma unroll
  for (int it = 0; it < 8; ++it) {
    int idx = it * 256 + tid;
    int rr = idx >> 4, s = idx & 15;
    uint4 d = *(const uint4*)(Wk_ + rr * 128 + s * 8);
    *(uint4*)(&Wlds[rr * 128 + ((s ^ (rr & 15)) << 3)]) = d;
  }
  __syncthreads();
  floatx4 acck[2][8];
#pragma unroll
  for (int mi = 0; mi < 2; ++mi)
#pragma unroll
    for (int ni = 0; ni < 8; ++ni) acck[mi][ni] = (floatx4){0.f, 0.f, 0.f, 0.f};
#pragma unroll
  for (int kk = 0; kk < 4; ++kk) {
    int seg = kk * 4 + l4;
    short8 a0 = *(const short8*)(&Alds[(wave * 32 + l15) * 128 + ((seg ^ l15) << 3)]);
    short8 a1 = *(const short8*)(&Alds[(wave * 32 + 16 + l15) * 128 + ((seg ^ l15) << 3)]);
#pragma unroll
    for (int ni = 0; ni < 8; ++ni) {
      short8 bfr = *(const short8*)(&Wlds[(ni * 16 + l15) * 128 + ((seg ^ l15) << 3)]);
      acck[0][ni] = __builtin_amdgcn_mfma_f32_16x16x32_bf16(a0, bfr, acck[0][ni], 0, 0, 0);
      acck[1][ni] = __builtin_amdgcn_mfma_f32_16x16x32_bf16(a1, bfr, acck[1][ni], 0, 0, 0);
    }
  }
  // ---- in-register weighted prefix scan over tokens (per channel) ----
  // token t = wave*32 + mi*16 + l4*4 + j; channel c = ni*16 + l15
  float Elr[2][8];    // exclusive within 16-token mi-group (before this lane's 4)
  float B0r[8];       // mi=0 group inclusive total
#pragma unroll
  for (int ni = 0; ni < 8; ++ni) {
    float d = dd[ni], d4 = d4a[ni];
    float d8 = d4 * d4, d16 = d8 * d8;
    float I[2];
#pragma unroll
    for (int mi = 0; mi < 2; ++mi) {
      float p0 = acck[mi][ni][0];
      float p1 = d * p0 + acck[mi][ni][1];
      float p2 = d * p1 + acck[mi][ni][2];
      float p3 = d * p2 + acck[mi][ni][3];
      acck[mi][ni][0] = p0; acck[mi][ni][1] = p1;
      acck[mi][ni][2] = p2; acck[mi][ni][3] = p3;
      float Iv = p3;
      float t1 = __shfl_up(Iv, 16);
      if (l4 >= 1) Iv += d4 * t1;
      float t2 = __shfl_up(Iv, 32);
      if (l4 >= 2) Iv += d8 * t2;
      float ex = __shfl_up(Iv, 16);
      Elr[mi][ni] = (l4 == 0) ? 0.f : ex;
      I[mi] = Iv;
    }
    float B0 = __shfl(I[0], 48 + l15);
    float B1 = __shfl(I[1], 48 + l15);
    B0r[ni] = B0;
    if (l4 == 0) SWT[wave * 128 + ni * 16 + l15] = B1 + d16 * B0;
  }
  __syncthreads();
  // ---- combine + y_local -> Wlds (reused as y staging, col-swizzled) ----
  u16* YW = Wlds;
#pragma unroll
  for (int ni = 0; ni < 8; ++ni) {
    int c = ni * 16 + l15;
    float d = dd[ni], d4 = d4a[ni];
    float d8 = d4 * d4, d12 = d8 * d4, d16 = d8 * d8, d32 = d16 * d16;
    float e = 0.f;
#pragma unroll
    for (int wv = 0; wv < 3; ++wv)
      if (wv < wave) e = e * d32 + SWT[wv * 128 + c];
    float d4l = (l4 == 0) ? 1.f : ((l4 == 1) ? d4 : ((l4 == 2) ? d8 : d12));
#pragma unroll
    for (int mi = 0; mi < 2; ++mi) {
      float Emi = (mi == 0) ? e : (e * d16 + B0r[ni]);
      float Sb = Elr[mi][ni] + d4l * Emi;
      float w = d;   // d^{j+1}
#pragma unroll
      for (int j = 0; j < 4; ++j) {
        float s = acck[mi][ni][j] + w * Sb;
        w *= d;
        float rvv = bf2f((u16)(rvp[mi][ni][j >> 1] >> ((j & 1) * 16)));
        float rss = bf2f((u16)(rp[mi][ni][j >> 1] >> ((j & 1) * 16)));
        float y = rvv + rss * s;
        int row = wave * 32 + mi * 16 + l4 * 4 + j;
        int colsw = c ^ (((row >> 2) & 3) << 4);
        YW[row * 128 + colsw] = f2bf(y);
      }
    }
  }
  if (tid < 128) {
    float a = fmaxf(td[tid], 0.f);
    float d32 = __expf(-32.f * a);
    float e = 0.f;
#pragma unroll
    for (int wv = 0; wv < 4; ++wv) e = e * d32 + SWT[wv * 128 + tid];
    Sbuf[(blockIdx.x & 127) * 1024 + (blockIdx.x >> 7) * 128 + tid] = e;
  }
  __syncthreads();
  // coalesced y_local store
#pragma unroll
  for (int it = 0; it < 8; ++it) {
    int idx = it * 256 + tid;
    int row = idx >> 4, cb = (idx & 15) * 8;
    int csw = cb ^ (((row >> 2) & 3) << 4);
    uint4 dv = *(const uint4*)(&YW[row * 128 + csw]);
    *(uint4*)(outY + (row0 + row) * 128 + cb) = dv;
  }
}

// ---------------------------------------------------------------------------
// Scan phase 2: per (b,c) scan over 128 chunks; one wave, 2 chunks per lane.
__global__ __launch_bounds__(256) void scan2_kernel(const float* __restrict__ S,
                                                    const float* __restrict__ td,
                                                    float* __restrict__ init) {
  int wave = threadIdx.x >> 6, lane = threadIdx.x & 63;
  int bc = blockIdx.x * 4 + wave;   // 0..1023
  int c = bc & 127;
  float a1 = __expf(-fmaxf(td[c], 0.f) * 128.f);   // decay^CLN
  float s0 = S[(2 * lane) * 1024 + bc];
  float s1 = S[(2 * lane + 1) * 1024 + bc];
  float s = s1 + a1 * s0;   // pair-combined segment sum
  float a = a1 * a1;
  for (int off = 1; off < 64; off <<= 1) {
    float ss = __shfl_up(s, off);
    float aa = __shfl_up(a, off);
    if (lane >= off) { s = s + a * ss; a = a * aa; }
  }
  float e = __shfl_up(s, 1);          // exclusive over pairs
  if (lane == 0) e = 0.f;
  init[(2 * lane) * 1024 + bc] = e;
  init[(2 * lane + 1) * 1024 + bc] = a1 * e + s0;
}

// ---------------------------------------------------------------------------
// Tail v4: y = y_local + rd*init (streamed) -> Y LDS -> t = Wo·y^T -> T2 ->
// g/bt GEMMs -> out = out*(1+tanh(g)) + bt. No scan. 32.5 KB LDS, 512 thr.
__global__ __launch_bounds__(512, 4) void tail_kernel(
    const u16* __restrict__ yl, const u16* __restrict__ rd,
    const float* __restrict__ init,
    const u16* __restrict__ Wo, const u16* __restrict__ Wg, const u16* __restrict__ Wb,
    const float* __restrict__ gpb, const float* __restrict__ bpb,
    float* __restrict__ outp) {
  __shared__ u32 SMEM[8192];          // 32 KB: Y -> T2 -> MB
  __shared__ float IL[128];
  u16* Y = (u16*)SMEM;
  u16* T2 = (u16*)SMEM;
  u32* MB = SMEM;

  int tid = threadIdx.x;
  int wave = tid >> 6, lane = tid & 63;
  int l15 = lane & 15, l4 = lane >> 4;
  int b = blockIdx.x >> 7;
  int chunk = blockIdx.x & 127;
  size_t ebase = ((size_t)b * 16384 + (size_t)chunk * 128) * 128;

  if (tid < 128) IL[tid] = init[chunk * 1024 + b * 128 + tid];
  __syncthreads();

  // ---- Y build: y = y_local + rd * init[c], swizzled into LDS ----
#pragma unroll
  for (int it = 0; it < 4; ++it) {
    int idx = it * 512 + tid;         // 0..2047
    int t = idx >> 4;
    int c8 = (idx & 15) * 8;
    uint4 yv = *(const uint4*)(yl + ebase + (size_t)t * 128 + c8);
    uint4 rv = *(const uint4*)(rd + ebase + (size_t)t * 128 + c8);
    u32 o[4];
    u32 yq[4] = {yv.x, yv.y, yv.z, yv.w};
    u32 rq[4] = {rv.x, rv.y, rv.z, rv.w};
#pragma unroll
    for (int q = 0; q < 4; ++q) {
      float y0 = bf2f((u16)(yq[q] & 0xffff)) + bf2f((u16)(rq[q] & 0xffff)) * IL[c8 + 2 * q];
      float y1 = bf2f((u16)(yq[q] >> 16)) + bf2f((u16)(rq[q] >> 16)) * IL[c8 + 2 * q + 1];
      o[q] = (u32)f2bf(y0) | ((u32)f2bf(y1) << 16);
    }
    uint4 ov = {o[0], o[1], o[2], o[3]};
    *(uint4*)(&Y[t * 128 + (((c8 >> 3) ^ (t & 15)) << 3)]) = ov;
  }
  __syncthreads();

  // ---- GEMM1: t[o][tok] = Wo(16 rows/wave) · Y^T ----
  int ob = wave * 16;
  short8 wof[4];
#pragma unroll
  for (int kk = 0; kk < 4; ++kk)
    wof[kk] = *(const short8*)(Wo + (ob + l15) * 128 + kk * 32 + l4 * 8);
  floatx4 acc[8];
#pragma unroll
  for (int ni = 0; ni < 8; ++ni) acc[ni] = (floatx4){0.f, 0.f, 0.f, 0.f};
#pragma unroll
  for (int kk = 0; kk < 4; ++kk) {
    int seg = kk * 4 + l4;
#pragma unroll
    for (int ni = 0; ni < 8; ++ni) {
      short8 yf = *(const short8*)(&Y[(ni * 16 + l15) * 128 + ((seg ^ l15) << 3)]);
      acc[ni] = __builtin_amdgcn_mfma_f32_16x16x32_bf16(wof[kk], yf, acc[ni], 0, 0, 0);
    }
  }
  __syncthreads();   // all Y reads complete before overwrite

  // write T2 [tok][o] bf16, swizzled, packed o-pairs
#pragma unroll
  for (int ni = 0; ni < 8; ++ni) {
    int tok = ni * 16 + l15;
#pragma unroll
    for (int j = 0; j < 4; j += 2) {
      int o = ob + l4 * 4 + j;
      u32 pack = (u32)f2bf(acc[ni][j]) | ((u32)f2bf(acc[ni][j + 1]) << 16);
      int pos = tok * 128 + ((((o >> 3) ^ (tok & 15)) << 3) | (o & 7));
      *(u32*)(T2 + pos) = pack;
    }
  }
  __syncthreads();

  // ---- GEMM2: g/bt [o'][tok] over K=o ----
  short8 wgf[4], wbf2[4];
#pragma unroll
  for (int kk = 0; kk < 4; ++kk) {
    wgf[kk]  = *(const short8*)(Wg + (ob + l15) * 128 + kk * 32 + l4 * 8);
    wbf2[kk] = *(const short8*)(Wb + (ob + l15) * 128 + kk * 32 + l4 * 8);
  }
  floatx4 ag[8], ab[8];
#pragma unroll
  for (int ni = 0; ni < 8; ++ni) {
    ag[ni] = (floatx4){0.f, 0.f, 0.f, 0.f};
    ab[ni] = (floatx4){0.f, 0.f, 0.f, 0.f};
  }
#pragma unroll
  for (int kk = 0; kk < 4; ++kk) {
    int seg = kk * 4 + l4;
#pragma unroll
    for (int ni = 0; ni < 8; ++ni) {
      short8 tf = *(const short8*)(&T2[(ni * 16 + l15) * 128 + ((seg ^ l15) << 3)]);
      ag[ni] = __builtin_amdgcn_mfma_f32_16x16x32_bf16(wgf[kk], tf, ag[ni], 0, 0, 0);
      ab[ni] = __builtin_amdgcn_mfma_f32_16x16x32_bf16(wbf2[kk], tf, ab[ni], 0, 0, 0);
    }
  }
  __syncthreads();   // T2 fully consumed

  // ---- Epilogue in two o-halves of 64 (MB = 32 KB) ----
#pragma unroll
  for (int h = 0; h < 2; ++h) {
    if ((wave >> 2) == h) {
      int orel0 = (wave & 3) * 16;
#pragma unroll
      for (int ni = 0; ni < 8; ++ni) {
        int tok = ni * 16 + l15;
#pragma unroll
        for (int j = 0; j < 4; ++j) {
          int orel = orel0 + l4 * 4 + j;
          int o = h * 64 + orel;
          float g = ag[ni][j] + gpb[o];
          float t1 = __expf(2.f * g);
          float m = 2.f - 2.f / (t1 + 1.f);          // 1 + tanh(g), inf-safe
          float bt = ab[ni][j] + bpb[o];
          int rot = ((orel & 3) << 2) | ((orel >> 2) & 3);
          MB[orel * 128 + ((((tok >> 3) ^ rot) << 3) | (tok & 7))] =
              (u32)f2bf(m) | ((u32)f2bf(bt) << 16);
        }
      }
    }
    __syncthreads();
#pragma unroll
    for (int it = 0; it < 2; ++it) {
      int idx = it * 512 + tid;
      int orel = idx >> 4, seg = idx & 15;
      int o = h * 64 + orel;
      int rot = ((orel & 3) << 2) | ((orel >> 2) & 3);
      int sp = ((seg ^ rot) << 3);
      uint4 mb0 = *(const uint4*)(&MB[orel * 128 + sp]);
      uint4 mb1 = *(const uint4*)(&MB[orel * 128 + sp + 4]);
      float* op = outp + ((size_t)(b * 128 + o)) * 16384 + chunk * 128 + seg * 8;
      float4 o0 = *(float4*)op;
      float4 o1 = *(float4*)(op + 4);
      o0.x = o0.x * bf2f((u16)(mb0.x & 0xffff)) + bf2f((u16)(mb0.x >> 16));
      o0.y = o0.y * bf2f((u16)(mb0.y & 0xffff)) + bf2f((u16)(mb0.y >> 16));
      o0.z = o0.z * bf2f((u16)(mb0.z & 0xffff)) + bf2f((u16)(mb0.z >> 16));
      o0.w = o0.w * bf2f((u16)(mb0.w & 0xffff)) + bf2f((u16)(mb0.w >> 16));
      o1.x = o1.x * bf2f((u16)(mb1.x & 0xffff)) + bf2f((u16)(mb1.x >> 16));
      o1.y = o1.y * bf2f((u16)(mb1.y & 0xffff)) + bf2f((u16)(mb1.y >> 16));
      o1.z = o1.z * bf2f((u16)(mb1.z & 0xffff)) + bf2f((u16)(mb1.z >> 16));
      o1.w = o1.w * bf2f((u16)(mb1.w & 0xffff)) + bf2f((u16)(mb1.w >> 16));
      *(float4*)op = o0;
      *(float4*)(op + 4) = o1;
    }
    __syncthreads();
  }
}

// ---------------------------------------------------------------------------
extern "C" void kernel_launch(void* const* d_in, const int* in_sizes, int n_in,
                              void* d_out, int out_size, void* d_ws, size_t ws_size,
                              hipStream_t stream) {
  const float* x        = (const float*)d_in[0];
  const float* gs       = (const float*)d_in[1];
  const float* cond_gw  = (const float*)d_in[2];
  const float* cond_gb  = (const float*)d_in[3];
  const float* cond_bw  = (const float*)d_in[4];
  const float* cond_bb  = (const float*)d_in[5];
  const float* td       = (const float*)d_in[6];
  const float* Wk       = (const float*)d_in[7];
  const float* Wv       = (const float*)d_in[8];
  const float* Wr       = (const float*)d_in[9];
  const float* Wo       = (const float*)d_in[10];
  const float* ln_g     = (const float*)d_in[11];
  const float* ln_b     = (const float*)d_in[12];
  const float* gp_w     = (const float*)d_in[13];
  const float* gp_b     = (const float*)d_in[14];
  const float* bp_w     = (const float*)d_in[15];
  const float* bp_b     = (const float*)d_in[16];
  float* outp = (float*)d_out;

  char* w = (char*)d_ws;
  float* gamma = (float*)w; w += 4096;
  float* beta  = (float*)w; w += 4096;
  u16* wbf     = (u16*)w;   w += 6 * 2 * 16384 * sizeof(u16);     // 384 KB
  u16* xn      = (u16*)w;   w += (size_t)MM * 128 * sizeof(u16);  // 32 MB
  u16* ybuf    = (u16*)w;   w += (size_t)MM * 128 * sizeof(u16);  // 32 MB
  u16* rdbuf   = (u16*)w;   w += (size_t)MM * 128 * sizeof(u16);  // 32 MB
  float* Sbuf  = (float*)w; w += NCH * 1024 * sizeof(float);      // 512 KB
  float* ibuf  = (float*)w; w += NCH * 1024 * sizeof(float);      // 512 KB

  film_kernel<<<4, 256, 0, stream>>>(gs, cond_gw, cond_gb, cond_bw, cond_bb, gamma, beta);
  convert_kernel<<<768, 256, 0, stream>>>(Wk, Wv, Wr, Wo, gp_w, bp_w, wbf);

  for (int blk = 0; blk < 2; ++blk) {
    const u16* bWk = wbf + 0 * 32768 + blk * 16384;
    const u16* bWv = wbf + 1 * 32768 + blk * 16384;
    const u16* bWr = wbf + 2 * 32768 + blk * 16384;
    const u16* bWo = wbf + 3 * 32768 + blk * 16384;
    const u16* bGp = wbf + 4 * 32768 + blk * 16384;
    const u16* bBp = wbf + 5 * 32768 + blk * 16384;
    const float* tdi = td + blk * 128;

    if (blk == 0)
      prep_kernel<1><<<2048, 256, 0, stream>>>(x, gamma, beta, ln_g, ln_b, outp, xn);
    else
      prep_kernel<0><<<2048, 256, 0, stream>>>(outp, nullptr, nullptr, ln_g + 128,
                                               ln_b + 128, nullptr, xn);

    gemm_y_kernel<<<1024, 256, 0, stream>>>(xn, bWv, bWr, bWk, tdi, ybuf, rdbuf, Sbuf);
    scan2_kernel<<<256, 256, 0, stream>>>(Sbuf, tdi, ibuf);
    tail_kernel<<<1024, 512, 0, stream>>>(ybuf, rdbuf, ibuf, bWo, bGp, bBp,
                                          gp_b + blk * 128, bp_b + blk * 128, outp);
  }
}